// Round 1
// baseline (410.953 us; speedup 1.0000x reference)
//
#include <hip/hip_runtime.h>
#include <math.h>

typedef unsigned int uint32;

#define NN      16384   // row length
#define THREADS 256
#define VPT     16      // float4 loads per thread (64 elements/thread)
#define NCOPY   16      // histogram copies to reduce LDS atomic contention
#define EQ_CAP  256     // capacity for ==threshold index list

__global__ __launch_bounds__(THREADS)
void imle_topk_kernel(const float* __restrict__ logits,
                      const float* __restrict__ noise,
                      const int*   __restrict__ kptr,
                      float*       __restrict__ out,
                      int Brows)
{
    const int row  = blockIdx.x;          // 0 .. S*B-1
    const int lrow = row % Brows;         // logits row
    const int tid  = threadIdx.x;
    const int k    = kptr[0];

    const float4* __restrict__ np4 = (const float4*)(noise  + (size_t)row  * NN);
    const float4* __restrict__ lp4 = (const float4*)(logits + (size_t)lrow * NN);
    float4*       __restrict__ op4 = (float4*)(out + (size_t)row * NN);

    // ---- 1. load + compute perturbed values as sortable uint keys (registers) ----
    uint32 key[VPT][4];

    #pragma unroll
    for (int j = 0; j < VPT; ++j) {
        const int v = tid + j * THREADS;
        const float4 u4 = np4[v];
        const float4 l4 = lp4[v];
        const float uu[4] = {u4.x, u4.y, u4.z, u4.w};
        const float ll[4] = {l4.x, l4.y, l4.z, l4.w};
        #pragma unroll
        for (int c = 0; c < 4; ++c) {
            // mirror reference fp32 rounding points; each log correctly rounded via double
            const float t1 = (float)log((double)uu[c]);      // log(u)
            const float t2 = (float)log((double)(-t1));      // log(-log(u))
            const float p  = ll[c] + (-t2);                  // logits + gumbel
            const uint32 b = __float_as_uint(p);
            key[j][c] = (b & 0x80000000u) ? ~b : (b | 0x80000000u);  // order-preserving
        }
    }

    // ---- 2. exact k-th largest via 4x8-bit radix select ----
    __shared__ int    hist[256 * NCOPY];
    __shared__ int    finalh[256];
    __shared__ uint32 sh_pref;
    __shared__ int    sh_rem;
    __shared__ int    eq_cnt;
    __shared__ int    eq_idx[EQ_CAP];

    if (tid == 0) eq_cnt = 0;

    uint32 prefix = 0;
    uint32 himask = 0;
    int    rem    = k;
    const int copy = tid & (NCOPY - 1);

    #pragma unroll
    for (int d = 3; d >= 0; --d) {
        const int sh = 8 * d;

        #pragma unroll
        for (int i = 0; i < (256 * NCOPY) / THREADS; ++i)
            hist[tid + i * THREADS] = 0;
        __syncthreads();

        #pragma unroll
        for (int j = 0; j < VPT; ++j) {
            #pragma unroll
            for (int c = 0; c < 4; ++c) {
                const uint32 kk = key[j][c];
                if ((kk & himask) == prefix)
                    atomicAdd(&hist[(((kk >> sh) & 255u) * NCOPY) + copy], 1);
            }
        }
        __syncthreads();

        {   // combine the NCOPY copies: one bin per thread
            int ssum = 0;
            #pragma unroll
            for (int q = 0; q < NCOPY; ++q) ssum += hist[tid * NCOPY + q];
            finalh[tid] = ssum;
        }
        __syncthreads();

        if (tid == 0) {
            int acc = 0;
            int bin = 255;
            for (; bin > 0; --bin) {          // suffix scan from the top
                const int h = finalh[bin];
                if (acc + h >= rem) break;
                acc += h;
            }
            sh_pref = prefix | ((uint32)bin << sh);
            sh_rem  = rem - acc;
        }
        __syncthreads();
        prefix = sh_pref;
        rem    = sh_rem;
        himask |= (0xFFu << sh);
    }

    const uint32 T     = prefix;   // exact key of the k-th largest
    const int    tneed = rem;      // how many ==T elements to select (lowest indices)

    // ---- 3. write mask; collect ==T indices ----
    #pragma unroll
    for (int j = 0; j < VPT; ++j) {
        const int v = tid + j * THREADS;
        float o[4];
        #pragma unroll
        for (int c = 0; c < 4; ++c) {
            const uint32 kk = key[j][c];
            o[c] = (kk > T) ? 1.0f : 0.0f;
            if (kk == T) {
                const int slot = atomicAdd(&eq_cnt, 1);
                if (slot < EQ_CAP) eq_idx[slot] = 4 * v + c;
            }
        }
        op4[v] = make_float4(o[0], o[1], o[2], o[3]);
    }
    __syncthreads();

    // ---- 4. tie-break: lowest tneed indices among ==T get 1.0 ----
    if (tid == 0) {
        int e = eq_cnt; if (e > EQ_CAP) e = EQ_CAP;
        float* orow = out + (size_t)row * NN;
        for (int it = 0; it < tneed; ++it) {
            int mn = 0x7FFFFFFF, mpos = -1;
            for (int q = 0; q < e; ++q) {
                const int idx = eq_idx[q];
                if (idx >= 0 && idx < mn) { mn = idx; mpos = q; }
            }
            if (mpos < 0) break;
            eq_idx[mpos] = -1;
            orow[mn] = 1.0f;
        }
    }
}

extern "C" void kernel_launch(void* const* d_in, const int* in_sizes, int n_in,
                              void* d_out, int out_size, void* d_ws, size_t ws_size,
                              hipStream_t stream) {
    const float* logits = (const float*)d_in[0];
    const float* noise  = (const float*)d_in[1];
    const int*   kptr   = (const int*)d_in[2];
    float*       out    = (float*)d_out;

    const int rows  = in_sizes[1] / NN;   // S*B = 2048
    const int Brows = in_sizes[0] / NN;   // B   = 128

    imle_topk_kernel<<<rows, THREADS, 0, stream>>>(logits, noise, kptr, out, Brows);
}